// Round 11
// baseline (1551.686 us; speedup 1.0000x reference)
//
#include <hip/hip_runtime.h>
#include <stdint.h>

typedef __bf16 bf16;
typedef __attribute__((ext_vector_type(8))) bf16 bf16x8;
typedef __attribute__((ext_vector_type(4))) bf16 bf16x4;
typedef __attribute__((ext_vector_type(4))) float f32x4;

#define T_DIM 512
#define H_DIM 4096
#define F_DIM 14336

// Tile = 128 rows x 64 cols bf16 = 16 KB, XOR-swizzled: elem = r*64 + (c ^ ((r&7)<<3)).
__device__ __forceinline__ int swz(int r, int c) {
    return r * 64 + (c ^ ((r & 7) << 3));
}

__device__ __forceinline__ int xcd_remap(int d, int chunk) {
    return (d & 7) * chunk + (d >> 3);
}

// async global->LDS, 16B/lane (down-proj only)
__device__ __forceinline__ void dma16(const void* g, void* l) {
    __builtin_amdgcn_global_load_lds(
        (const __attribute__((address_space(1))) void*)g,
        (__attribute__((address_space(3))) void*)l, 16, 0, 0);
}

#define BARRIER_VM(N)                                                        \
    {                                                                        \
        __builtin_amdgcn_sched_barrier(0);                                   \
        asm volatile("s_waitcnt vmcnt(" #N ") lgkmcnt(0)\n\ts_barrier" ::: "memory"); \
        __builtin_amdgcn_sched_barrier(0);                                   \
    }

// dequant 8 consecutive elements (two int4 + two float4 pairs) -> bf16x8
__device__ __forceinline__ bf16x8 deq8(int4 qa, int4 qb, float4 sa, float4 sb,
                                       float4 za, float4 zb) {
    bf16x8 r;
    r[0] = (bf16)(((float)qa.x - za.x) * sa.x);
    r[1] = (bf16)(((float)qa.y - za.y) * sa.y);
    r[2] = (bf16)(((float)qa.z - za.z) * sa.z);
    r[3] = (bf16)(((float)qa.w - za.w) * sa.w);
    r[4] = (bf16)(((float)qb.x - zb.x) * sb.x);
    r[5] = (bf16)(((float)qb.y - zb.y) * sb.y);
    r[6] = (bf16)(((float)qb.z - zb.z) * sb.z);
    r[7] = (bf16)(((float)qb.w - zb.w) * sb.w);
    return r;
}

// ---------------------------------------------------------------------------
// x (f32 [512][4096]) -> xb tiled: [panel p=m>>7][ktile c>>6][swz(r,c) tile]
__global__ void cvt_x_kernel(const float* __restrict__ x, bf16* __restrict__ xbt) {
    int i = (blockIdx.x * 256 + threadIdx.x) * 4;
    int m = i >> 12;
    int c = i & 4095;
    float4 v = *(const float4*)(x + i);
    bf16x4 o = {(bf16)v.x, (bf16)v.y, (bf16)v.z, (bf16)v.w};
    int p = m >> 7, rm = m & 127, kt = c >> 6, kc = c & 63;
    *(bf16x4*)(xbt + (size_t)(p * 64 + kt) * 8192 + swz(rm, kc)) = o;
}

// ---------------------------------------------------------------------------
// Fused gate+up — BARRIER-FREE, LDS-FREE. Each wave owns a 64(M)x16(N) output
// of both GEMMs and streams K independently:
//   A-frags:  direct bf16x8 loads from tiled xb (4 MB, L2/L3-resident)
//   B-frags:  per-lane W row (n = n0+lane&15), int32 loads -> dequant in regs
// q staged 2 steps ahead (2 named sets), s/z staged 1 step ahead.
// Block = 4 waves = 4 n-quarters of one (m-panel, n-64) tile; grid 8x224=1792.
struct QSet { int4 q1[4], q3[4]; };   // [kk*2+h]

__global__ __launch_bounds__(256, 2)
void gemm_gateup(const bf16* __restrict__ A,   // tiled xb
                 const int* __restrict__ Wq1, const float* __restrict__ Sc1,
                 const float* __restrict__ Zr1,
                 const int* __restrict__ Wq3, const float* __restrict__ Sc3,
                 const float* __restrict__ Zr3,
                 bf16* __restrict__ inter) {   // tiled output
    constexpr int KD = H_DIM;
    constexpr int NT = KD / 64;                 // 64 (even)

    const int l    = xcd_remap(blockIdx.x, 224);
    const int mp   = l & 7;                     // m-panel (64 rows); 8 mp share W -> co-XCD
    const int np   = l >> 3;                    // n-panel (64 cols) 0..223
    const int tid  = threadIdx.x;
    const int lane = tid & 63;
    const int w    = tid >> 6;                  // n-quarter
    const int lr   = lane & 15;
    const int lk   = (lane >> 4) * 8;
    const int n0   = np * 64 + w * 16;
    const int rowW = n0 + lr;                   // this lane's W row

    const bf16* at0 = A + (size_t)(mp >> 1) * 64 * 8192;
    const int   rmb = (mp & 1) * 64;

    // per-lane constant swizzled A offsets
    int aoff[4][2];
#pragma unroll
    for (int mi = 0; mi < 4; mi++)
#pragma unroll
        for (int kk = 0; kk < 2; kk++)
            aoff[mi][kk] = swz(rmb + mi * 16 + lr, kk * 32 + lk);

    const int*   q1B = Wq1 + (size_t)rowW * KD + lk;
    const int*   q3B = Wq3 + (size_t)rowW * KD + lk;
    const float* s1B = Sc1 + (size_t)np * KD + lk;
    const float* z1B = Zr1 + (size_t)np * KD + lk;
    const float* s3B = Sc3 + (size_t)np * KD + lk;
    const float* z3B = Zr3 + (size_t)np * KD + lk;

    f32x4 acc1[4], acc3[4];
    const f32x4 zf = {0.f, 0.f, 0.f, 0.f};
#pragma unroll
    for (int i = 0; i < 4; i++) { acc1[i] = zf; acc3[i] = zf; }

    QSet  qa, qb;
    float4 s1[4], z1[4], s3[4], z3[4];          // s/z set (refilled every sub-step)

#define QST(S, K0)                                                            \
    {                                                                         \
        _Pragma("unroll")                                                     \
        for (int kk = 0; kk < 2; kk++)                                        \
            _Pragma("unroll")                                                 \
            for (int h = 0; h < 2; h++) {                                     \
                S.q1[kk * 2 + h] = *(const int4*)(q1B + (K0) + kk * 32 + h * 4); \
                S.q3[kk * 2 + h] = *(const int4*)(q3B + (K0) + kk * 32 + h * 4); \
            }                                                                 \
    }

#define SZST(K0)                                                              \
    {                                                                         \
        _Pragma("unroll")                                                     \
        for (int kk = 0; kk < 2; kk++)                                        \
            _Pragma("unroll")                                                 \
            for (int h = 0; h < 2; h++) {                                     \
                int o = (K0) + kk * 32 + h * 4;                               \
                s1[kk * 2 + h] = *(const float4*)(s1B + o);                   \
                z1[kk * 2 + h] = *(const float4*)(z1B + o);                   \
                s3[kk * 2 + h] = *(const float4*)(s3B + o);                   \
                z3[kk * 2 + h] = *(const float4*)(z3B + o);                   \
            }                                                                 \
    }

#define BODY(S, T)                                                            \
    {                                                                         \
        const bf16* at = at0 + (size_t)(T) * 8192;                            \
        bf16x8 a_[4][2];                                                      \
        _Pragma("unroll")                                                     \
        for (int mi = 0; mi < 4; mi++)                                        \
            _Pragma("unroll")                                                 \
            for (int kk = 0; kk < 2; kk++)                                    \
                a_[mi][kk] = *(const bf16x8*)(at + aoff[mi][kk]);             \
        bf16x8 b1f[2], b3f[2];                                                \
        _Pragma("unroll")                                                     \
        for (int kk = 0; kk < 2; kk++) {                                      \
            b1f[kk] = deq8(S.q1[kk * 2], S.q1[kk * 2 + 1], s1[kk * 2],        \
                           s1[kk * 2 + 1], z1[kk * 2], z1[kk * 2 + 1]);       \
            b3f[kk] = deq8(S.q3[kk * 2], S.q3[kk * 2 + 1], s3[kk * 2],        \
                           s3[kk * 2 + 1], z3[kk * 2], z3[kk * 2 + 1]);       \
        }                                                                     \
        if ((T) + 2 < NT) QST(S, ((T) + 2) * 64);                             \
        if ((T) + 1 < NT) SZST(((T) + 1) * 64);                               \
        _Pragma("unroll")                                                     \
        for (int kk = 0; kk < 2; kk++)                                        \
            _Pragma("unroll")                                                 \
            for (int mi = 0; mi < 4; mi++) {                                  \
                acc1[mi] = __builtin_amdgcn_mfma_f32_16x16x32_bf16(a_[mi][kk], b1f[kk], acc1[mi], 0, 0, 0); \
                acc3[mi] = __builtin_amdgcn_mfma_f32_16x16x32_bf16(a_[mi][kk], b3f[kk], acc3[mi], 0, 0, 0); \
            }                                                                 \
    }

    // Prologue: q for steps 0 and 1 in flight; s/z for step 0.
    QST(qa, 0);
    QST(qb, 64);
    SZST(0);

    for (int t = 0; t < NT; t += 2) {
        BODY(qa, t);
        BODY(qb, t + 1);
    }
#undef QST
#undef SZST
#undef BODY

    // Epilogue: silu(gate)*up -> tiled inter (independent per wave, no sync).
    const int orow = (lane >> 4) * 4;
    const int cg   = n0 + lr;
    const int kt   = cg >> 6, kc = cg & 63;
    bf16* itile = inter + (size_t)((mp >> 1) * 224 + kt) * 8192;
#pragma unroll
    for (int mi = 0; mi < 4; mi++) {
#pragma unroll
        for (int r = 0; r < 4; r++) {
            int rm2 = rmb + mi * 16 + orow + r;
            float g = acc1[mi][r];
            float u = acc3[mi][r];
            float s = g / (1.0f + __expf(-g));
            itile[swz(rm2, kc)] = (bf16)(s * u);
        }
    }
}

// ---------------------------------------------------------------------------
// Down proj (round-10 proven version): split-K, DMA'd tiled A, reg-staged W,
// counted-vmcnt barriers.
struct WSetD { int4 q[2]; float4 s, z; };

template<int SPLITK>
__global__ __launch_bounds__(256, 4)
void gemm_down(const bf16* __restrict__ A,    // tiled inter
               const int* __restrict__ Wq,
               const float* __restrict__ Sc, const float* __restrict__ Zr,
               float* __restrict__ partials) {
    constexpr int KD = F_DIM;
    constexpr int KC = KD / SPLITK;
    constexpr int NT = KC / 64;
    __shared__ __align__(16) bf16 As[2][128 * 64];
    __shared__ __align__(16) bf16 Bs[2][32 * 64];

    const int l    = xcd_remap(blockIdx.x, 64 * SPLITK);
    const int bx   = l & 3;
    const int by   = (l >> 2) & 127;
    const int bz   = l >> 9;
    const int tid  = threadIdx.x;
    const int lane = tid & 63;
    const int wid  = tid >> 6;
    const int wm   = wid >> 1, wn = wid & 1;
    const int lr   = lane & 15;
    const int lk   = (lane >> 4) * 8;
    const int m0   = bx * 128;
    const int n0   = by * 32;
    const int grp  = n0 >> 6;
    const int kt0  = bz * (KC / 64);

    const int b_r = (tid >> 4) * 2;
    const int b_c = (tid & 15) * 4;

    const char*  atile = (const char*)A + (size_t)(bx * 224 + kt0) * 16384;
    const size_t dmaoff = (size_t)wid * 4096 + lane * 16;
    const int    kbeg  = bz * KC;

    const int*   qB  = Wq + (size_t)(n0 + b_r) * KD + kbeg + b_c;
    const float* sB_ = Sc + (size_t)grp * KD + kbeg + b_c;
    const float* zB_ = Zr + (size_t)grp * KD + kbeg + b_c;

    f32x4 acc[4];
    const f32x4 zf = {0.f, 0.f, 0.f, 0.f};
#pragma unroll
    for (int i = 0; i < 4; i++) acc[i] = zf;

    WSetD sA, sB;

#define GD_DMA(TILE, nb)                                                      \
    {                                                                         \
        const char* _s = atile + (size_t)(TILE) * 16384 + dmaoff;             \
        char* _d = (char*)&As[nb][0] + wid * 4096;                            \
        _Pragma("unroll")                                                     \
        for (int j = 0; j < 4; j++) dma16(_s + j * 1024, _d + j * 1024);      \
    }

#define GD_STAGE(S, K0)                                                       \
    {                                                                         \
        _Pragma("unroll")                                                     \
        for (int i = 0; i < 2; i++)                                           \
            S.q[i] = *(const int4*)(qB + (size_t)i * KD + (K0));              \
        S.s = *(const float4*)(sB_ + (K0));                                   \
        S.z = *(const float4*)(zB_ + (K0));                                   \
    }

#define GD_WLDS(S, nb)                                                        \
    {                                                                         \
        float4 nz;                                                            \
        nz.x = -S.z.x * S.s.x; nz.y = -S.z.y * S.s.y;                         \
        nz.z = -S.z.z * S.s.z; nz.w = -S.z.w * S.s.w;                         \
        _Pragma("unroll")                                                     \
        for (int i = 0; i < 2; i++) {                                         \
            bf16x4 v;                                                         \
            v[0] = (bf16)fmaf((float)S.q[i].x, S.s.x, nz.x);                  \
            v[1] = (bf16)fmaf((float)S.q[i].y, S.s.y, nz.y);                  \
            v[2] = (bf16)fmaf((float)S.q[i].z, S.s.z, nz.z);                  \
            v[3] = (bf16)fmaf((float)S.q[i].w, S.s.w, nz.w);                  \
            *(bf16x4*)&Bs[nb][swz(b_r + i, b_c)] = v;                         \
        }                                                                     \
    }

#define GD_MFMA(nb)                                                           \
    {                                                                         \
        _Pragma("unroll")                                                     \
        for (int kk = 0; kk < 2; kk++) {                                      \
            bf16x8 af[4], bfr;                                                \
            _Pragma("unroll")                                                 \
            for (int mi = 0; mi < 4; mi++)                                    \
                af[mi] = *(const bf16x8*)&As[nb][swz(wm * 64 + mi * 16 + lr, kk * 32 + lk)]; \
            bfr = *(const bf16x8*)&Bs[nb][swz(wn * 16 + lr, kk * 32 + lk)];   \
            _Pragma("unroll")                                                 \
            for (int mi = 0; mi < 4; mi++)                                    \
                acc[mi] = __builtin_amdgcn_mfma_f32_16x16x32_bf16(af[mi], bfr, acc[mi], 0, 0, 0); \
        }                                                                     \
    }

    GD_STAGE(sA, 0);
    GD_DMA(0, 0);
    GD_WLDS(sA, 0);
    GD_STAGE(sB, 64);
    GD_STAGE(sA, 128);
    BARRIER_VM(8);

    for (int t = 0; t < NT; t += 2) {
        if (t + 1 < NT) GD_DMA(t + 1, 1);
        __builtin_amdgcn_sched_barrier(0);
        GD_MFMA(0);
        if (t + 1 < NT) {
            GD_WLDS(sB, 1);
            if (t + 3 < NT) {
                GD_STAGE(sB, (t + 3) * 64);
                BARRIER_VM(4);
            } else {
                BARRIER_VM(0);
            }
        }
        const int u = t + 1;
        if (u < NT) {
            if (u + 1 < NT) GD_DMA(u + 1, 0);
            __builtin_amdgcn_sched_barrier(0);
            GD_MFMA(1);
            if (u + 1 < NT) {
                GD_WLDS(sA, 0);
                if (u + 3 < NT) {
                    GD_STAGE(sA, (u + 3) * 64);
                    BARRIER_VM(4);
                } else {
                    BARRIER_VM(0);
                }
            }
        }
    }
#undef GD_DMA
#undef GD_STAGE
#undef GD_WLDS
#undef GD_MFMA

    float* po = partials + (size_t)bz * T_DIM * H_DIM;
    const int orow = (lane >> 4) * 4;
#pragma unroll
    for (int mi = 0; mi < 4; mi++) {
#pragma unroll
        for (int r = 0; r < 4; r++) {
            int m = m0 + wm * 64 + mi * 16 + orow + r;
            int c = n0 + wn * 16 + lr;
            po[(size_t)m * H_DIM + c] = acc[mi][r];
        }
    }
}

// ---------------------------------------------------------------------------
template<int S>
__global__ void reduce_kernel(const float* __restrict__ partials, float* __restrict__ out) {
    size_t i = ((size_t)blockIdx.x * 256 + threadIdx.x) * 4;
    f32x4 a = *(const f32x4*)(partials + i);
#pragma unroll
    for (int s = 1; s < S; s++)
        a += *(const f32x4*)(partials + (size_t)s * T_DIM * H_DIM + i);
    *(f32x4*)(out + i) = a;
}

// ---------------------------------------------------------------------------
extern "C" void kernel_launch(void* const* d_in, const int* in_sizes, int n_in,
                              void* d_out, int out_size, void* d_ws, size_t ws_size,
                              hipStream_t stream) {
    const float* x   = (const float*)d_in[0];
    const int*   w1q = (const int*)d_in[1];
    const float* w1s = (const float*)d_in[2];
    const float* w1z = (const float*)d_in[3];
    const int*   w2q = (const int*)d_in[4];
    const float* w2s = (const float*)d_in[5];
    const float* w2z = (const float*)d_in[6];
    const int*   w3q = (const int*)d_in[7];
    const float* w3s = (const float*)d_in[8];
    const float* w3z = (const float*)d_in[9];

    bf16*  xb    = (bf16*)d_ws;                         // tiled [4][64][8192]
    bf16*  inter = xb + (size_t)T_DIM * H_DIM;          // tiled [4][224][8192]
    float* parts = (float*)(inter + (size_t)T_DIM * F_DIM);

    const size_t base   = (size_t)T_DIM * H_DIM * 2 + (size_t)T_DIM * F_DIM * 2;
    const size_t pbytes = (size_t)T_DIM * H_DIM * 4;

    cvt_x_kernel<<<dim3(2048), dim3(256), 0, stream>>>(x, xb);

    // gateup: 8 m-panels x 224 n-panels = 1792 blocks, XCD-remapped
    gemm_gateup<<<dim3(1792), dim3(256), 0, stream>>>(
        xb, w1q, w1s, w1z, w3q, w3s, w3z, inter);

    if (ws_size >= base + 4 * pbytes) {
        gemm_down<4><<<dim3(2048), dim3(256), 0, stream>>>(inter, w2q, w2s, w2z, parts);
        reduce_kernel<4><<<dim3(2048), dim3(256), 0, stream>>>(parts, (float*)d_out);
    } else if (ws_size >= base + 2 * pbytes) {
        gemm_down<2><<<dim3(1024), dim3(256), 0, stream>>>(inter, w2q, w2s, w2z, parts);
        reduce_kernel<2><<<dim3(2048), dim3(256), 0, stream>>>(parts, (float*)d_out);
    } else {
        gemm_down<1><<<dim3(512), dim3(256), 0, stream>>>(inter, w2q, w2s, w2z, parts);
        reduce_kernel<1><<<dim3(2048), dim3(256), 0, stream>>>(parts, (float*)d_out);
    }
}

// Round 12
// 1306.938 us; speedup vs baseline: 1.1873x; 1.1873x over previous
//
#include <hip/hip_runtime.h>
#include <stdint.h>

typedef __bf16 bf16;
typedef __attribute__((ext_vector_type(8))) bf16 bf16x8;
typedef __attribute__((ext_vector_type(4))) bf16 bf16x4;
typedef __attribute__((ext_vector_type(4))) float f32x4;

#define T_DIM 512
#define H_DIM 4096
#define F_DIM 14336

// Tile = 128 rows x 64 cols bf16 = 16 KB, XOR-swizzled: elem = r*64 + (c ^ ((r&7)<<3)).
__device__ __forceinline__ int swz(int r, int c) {
    return r * 64 + (c ^ ((r & 7) << 3));
}

__device__ __forceinline__ int xcd_remap(int d, int chunk) {
    return (d & 7) * chunk + (d >> 3);
}

// Race-safe no-vmcnt-drain barrier (validated rounds 7/9/10).
__device__ __forceinline__ void barrier_nodrain() {
    __builtin_amdgcn_sched_barrier(0);
    asm volatile("s_waitcnt lgkmcnt(0)\n\ts_barrier" ::: "memory");
    __builtin_amdgcn_sched_barrier(0);
}

// ---------------------------------------------------------------------------
// x (f32 [512][4096]) -> xb tiled: [panel p=m>>7][ktile c>>6][swz(r,c) tile]
__global__ void cvt_x_kernel(const float* __restrict__ x, bf16* __restrict__ xbt) {
    int i = (blockIdx.x * 256 + threadIdx.x) * 4;
    int m = i >> 12;
    int c = i & 4095;
    float4 v = *(const float4*)(x + i);
    bf16x4 o = {(bf16)v.x, (bf16)v.y, (bf16)v.z, (bf16)v.w};
    int p = m >> 7, rm = m & 127, kt = c >> 6, kc = c & 63;
    *(bf16x4*)(xbt + (size_t)(p * 64 + kt) * 8192 + swz(rm, kc)) = o;
}

// ---------------------------------------------------------------------------
// Fused gate+up: inter = silu(x@W1^T) * (x@W3^T).
// Tile 128(M) x 32(N), BK=64, 4 waves (2M x 2N). A read DIRECT from tiled xb
// (L2/L3-hot, verified pattern r11). B dequant -> dbuf LDS (16 KB only).
// Weights q staged 2-deep (qa/qb), s/z 1-deep. One nodrain barrier/step.
struct QSet { int4 q1[2], q3[2]; };

__global__ __launch_bounds__(256, 4)
void gemm_gateup(const bf16* __restrict__ A,   // tiled xb
                 const int* __restrict__ Wq1, const float* __restrict__ Sc1,
                 const float* __restrict__ Zr1,
                 const int* __restrict__ Wq3, const float* __restrict__ Sc3,
                 const float* __restrict__ Zr3,
                 bf16* __restrict__ inter) {   // tiled output
    constexpr int KD = H_DIM;
    constexpr int NT = KD / 64;                    // 64 (even)
    __shared__ __align__(16) bf16 Bs1[2][32 * 64]; // 8 KB
    __shared__ __align__(16) bf16 Bs3[2][32 * 64]; // 8 KB

    const int l    = xcd_remap(blockIdx.x, 224);
    const int bx   = l & 3;                        // M panel (replicas co-XCD)
    const int by   = l >> 2;                       // N block 0..447
    const int tid  = threadIdx.x;
    const int lane = tid & 63;
    const int wid  = tid >> 6;
    const int wm   = wid >> 1, wn = wid & 1;
    const int lr   = lane & 15;
    const int lk   = (lane >> 4) * 8;
    const int n0   = by * 32;
    const int grp  = n0 >> 6;

    const int b_r = (tid >> 4) * 2;
    const int b_c = (tid & 15) * 4;

    const bf16* at0 = A + (size_t)bx * 64 * 8192;  // this panel's 64 ktiles

    // per-lane constant swizzled A offsets (verified r11)
    int aoff[4][2];
#pragma unroll
    for (int mi = 0; mi < 4; mi++)
#pragma unroll
        for (int kk = 0; kk < 2; kk++)
            aoff[mi][kk] = swz(wm * 64 + mi * 16 + lr, kk * 32 + lk);

    const int*   q1B = Wq1 + (size_t)(n0 + b_r) * KD + b_c;
    const int*   q3B = Wq3 + (size_t)(n0 + b_r) * KD + b_c;
    const float* s1B = Sc1 + (size_t)grp * KD + b_c;
    const float* z1B = Zr1 + (size_t)grp * KD + b_c;
    const float* s3B = Sc3 + (size_t)grp * KD + b_c;
    const float* z3B = Zr3 + (size_t)grp * KD + b_c;

    f32x4 acc1[4], acc3[4];
    const f32x4 zf = {0.f, 0.f, 0.f, 0.f};
#pragma unroll
    for (int i = 0; i < 4; i++) { acc1[i] = zf; acc3[i] = zf; }

    QSet qa, qb;
    float4 s1r, z1r, s3r, z3r;

#define QST(S, K0)                                                            \
    {                                                                         \
        _Pragma("unroll")                                                     \
        for (int i = 0; i < 2; i++) {                                         \
            S.q1[i] = *(const int4*)(q1B + (size_t)i * KD + (K0));            \
            S.q3[i] = *(const int4*)(q3B + (size_t)i * KD + (K0));            \
        }                                                                     \
    }

#define SZST(K0)                                                              \
    {                                                                         \
        s1r = *(const float4*)(s1B + (K0));                                   \
        z1r = *(const float4*)(z1B + (K0));                                   \
        s3r = *(const float4*)(s3B + (K0));                                   \
        z3r = *(const float4*)(z3B + (K0));                                   \
    }

#define WLDS(S, nb)                                                           \
    {                                                                         \
        float4 n1, n3;                                                        \
        n1.x = -z1r.x * s1r.x; n1.y = -z1r.y * s1r.y;                         \
        n1.z = -z1r.z * s1r.z; n1.w = -z1r.w * s1r.w;                         \
        n3.x = -z3r.x * s3r.x; n3.y = -z3r.y * s3r.y;                         \
        n3.z = -z3r.z * s3r.z; n3.w = -z3r.w * s3r.w;                         \
        _Pragma("unroll")                                                     \
        for (int i = 0; i < 2; i++) {                                         \
            bf16x4 v;                                                         \
            v[0] = (bf16)fmaf((float)S.q1[i].x, s1r.x, n1.x);                 \
            v[1] = (bf16)fmaf((float)S.q1[i].y, s1r.y, n1.y);                 \
            v[2] = (bf16)fmaf((float)S.q1[i].z, s1r.z, n1.z);                 \
            v[3] = (bf16)fmaf((float)S.q1[i].w, s1r.w, n1.w);                 \
            *(bf16x4*)&Bs1[nb][swz(b_r + i, b_c)] = v;                        \
            bf16x4 u;                                                         \
            u[0] = (bf16)fmaf((float)S.q3[i].x, s3r.x, n3.x);                 \
            u[1] = (bf16)fmaf((float)S.q3[i].y, s3r.y, n3.y);                 \
            u[2] = (bf16)fmaf((float)S.q3[i].z, s3r.z, n3.z);                 \
            u[3] = (bf16)fmaf((float)S.q3[i].w, s3r.w, n3.w);                 \
            *(bf16x4*)&Bs3[nb][swz(b_r + i, b_c)] = u;                        \
        }                                                                     \
    }

// One K-step: MFMA on Bs[T&1] + direct-A(tile T); then stage W(T+1) into
// Bs[(T+1)&1], refill q (T+3) and sz (T+2); single nodrain barrier.
#define GU_STEP(T, QS)                                                        \
    {                                                                         \
        const bf16* at = at0 + (size_t)(T) * 8192;                            \
        _Pragma("unroll")                                                     \
        for (int kk = 0; kk < 2; kk++) {                                      \
            bf16x8 a0 = *(const bf16x8*)(at + aoff[0][kk]);                   \
            bf16x8 a1 = *(const bf16x8*)(at + aoff[1][kk]);                   \
            bf16x8 a2 = *(const bf16x8*)(at + aoff[2][kk]);                   \
            bf16x8 a3 = *(const bf16x8*)(at + aoff[3][kk]);                   \
            bf16x8 b1 = *(const bf16x8*)&Bs1[(T) & 1][swz(wn * 16 + lr, kk * 32 + lk)]; \
            bf16x8 b3 = *(const bf16x8*)&Bs3[(T) & 1][swz(wn * 16 + lr, kk * 32 + lk)]; \
            acc1[0] = __builtin_amdgcn_mfma_f32_16x16x32_bf16(a0, b1, acc1[0], 0, 0, 0); \
            acc3[0] = __builtin_amdgcn_mfma_f32_16x16x32_bf16(a0, b3, acc3[0], 0, 0, 0); \
            acc1[1] = __builtin_amdgcn_mfma_f32_16x16x32_bf16(a1, b1, acc1[1], 0, 0, 0); \
            acc3[1] = __builtin_amdgcn_mfma_f32_16x16x32_bf16(a1, b3, acc3[1], 0, 0, 0); \
            acc1[2] = __builtin_amdgcn_mfma_f32_16x16x32_bf16(a2, b1, acc1[2], 0, 0, 0); \
            acc3[2] = __builtin_amdgcn_mfma_f32_16x16x32_bf16(a2, b3, acc3[2], 0, 0, 0); \
            acc1[3] = __builtin_amdgcn_mfma_f32_16x16x32_bf16(a3, b1, acc1[3], 0, 0, 0); \
            acc3[3] = __builtin_amdgcn_mfma_f32_16x16x32_bf16(a3, b3, acc3[3], 0, 0, 0); \
        }                                                                     \
        if ((T) + 1 < NT) {                                                   \
            WLDS(QS, ((T) + 1) & 1);                                          \
            if ((T) + 3 < NT) QST(QS, ((T) + 3) * 64);                        \
            if ((T) + 2 < NT) SZST(((T) + 2) * 64);                           \
            barrier_nodrain();                                                \
        }                                                                     \
    }

    // Prologue: W0 -> Bs[0]; W1 (qa) and W2 (qb) in flight; sz(1) staged.
    QST(qa, 0);
    SZST(0);
    WLDS(qa, 0);
    QST(qa, 64);
    QST(qb, 128);
    SZST(64);
    barrier_nodrain();

    for (int t = 0; t < NT; t += 2) {
        GU_STEP(t, qa);
        GU_STEP(t + 1, qb);
    }
#undef QST
#undef SZST
#undef WLDS
#undef GU_STEP

    // Epilogue: silu(gate)*up -> tiled inter (verified r10/r11).
    const int orow = (lane >> 4) * 4;
    const int cg   = n0 + wn * 16 + lr;
    const int kt   = cg >> 6, kc = cg & 63;
    bf16* itile = inter + (size_t)(bx * 224 + kt) * 8192;
#pragma unroll
    for (int mi = 0; mi < 4; mi++) {
#pragma unroll
        for (int r = 0; r < 4; r++) {
            int rm = wm * 64 + mi * 16 + orow + r;
            float g = acc1[mi][r];
            float u = acc3[mi][r];
            float s = g / (1.0f + __expf(-g));
            itile[swz(rm, kc)] = (bf16)(s * u);
        }
    }
}

// ---------------------------------------------------------------------------
// Down proj, split-K. Same structure, single weight; A direct from tiled inter.
struct QSetD { int4 q[2]; };

template<int SPLITK>
__global__ __launch_bounds__(256, 4)
void gemm_down(const bf16* __restrict__ A,    // tiled inter
               const int* __restrict__ Wq,
               const float* __restrict__ Sc, const float* __restrict__ Zr,
               float* __restrict__ partials) {
    constexpr int KD = F_DIM;
    constexpr int KC = KD / SPLITK;
    constexpr int NT = KC / 64;                    // 56 (even)
    __shared__ __align__(16) bf16 Bs[2][32 * 64];  // 8 KB

    const int l    = xcd_remap(blockIdx.x, 64 * SPLITK);
    const int bx   = l & 3;
    const int by   = (l >> 2) & 127;
    const int bz   = l >> 9;
    const int tid  = threadIdx.x;
    const int lane = tid & 63;
    const int wid  = tid >> 6;
    const int wm   = wid >> 1, wn = wid & 1;
    const int lr   = lane & 15;
    const int lk   = (lane >> 4) * 8;
    const int m0   = bx * 128;
    const int n0   = by * 32;
    const int grp  = n0 >> 6;
    const int kt0  = bz * (KC / 64);
    const int kbeg = bz * KC;

    const int b_r = (tid >> 4) * 2;
    const int b_c = (tid & 15) * 4;

    const bf16* at0 = A + (size_t)(bx * 224 + kt0) * 8192;

    int aoff[4][2];
#pragma unroll
    for (int mi = 0; mi < 4; mi++)
#pragma unroll
        for (int kk = 0; kk < 2; kk++)
            aoff[mi][kk] = swz(wm * 64 + mi * 16 + lr, kk * 32 + lk);

    const int*   qB  = Wq + (size_t)(n0 + b_r) * KD + kbeg + b_c;
    const float* sB_ = Sc + (size_t)grp * KD + kbeg + b_c;
    const float* zB_ = Zr + (size_t)grp * KD + kbeg + b_c;

    f32x4 acc[4];
    const f32x4 zf = {0.f, 0.f, 0.f, 0.f};
#pragma unroll
    for (int i = 0; i < 4; i++) acc[i] = zf;

    QSetD qa, qb;
    float4 sr, zr;

#define QST(S, K0)                                                            \
    {                                                                         \
        _Pragma("unroll")                                                     \
        for (int i = 0; i < 2; i++)                                           \
            S.q[i] = *(const int4*)(qB + (size_t)i * KD + (K0));              \
    }

#define SZST(K0)                                                              \
    {                                                                         \
        sr = *(const float4*)(sB_ + (K0));                                    \
        zr = *(const float4*)(zB_ + (K0));                                    \
    }

#define WLDS(S, nb)                                                           \
    {                                                                         \
        float4 nz;                                                            \
        nz.x = -zr.x * sr.x; nz.y = -zr.y * sr.y;                             \
        nz.z = -zr.z * sr.z; nz.w = -zr.w * sr.w;                             \
        _Pragma("unroll")                                                     \
        for (int i = 0; i < 2; i++) {                                         \
            bf16x4 v;                                                         \
            v[0] = (bf16)fmaf((float)S.q[i].x, sr.x, nz.x);                   \
            v[1] = (bf16)fmaf((float)S.q[i].y, sr.y, nz.y);                   \
            v[2] = (bf16)fmaf((float)S.q[i].z, sr.z, nz.z);                   \
            v[3] = (bf16)fmaf((float)S.q[i].w, sr.w, nz.w);                   \
            *(bf16x4*)&Bs[nb][swz(b_r + i, b_c)] = v;                         \
        }                                                                     \
    }

#define GD_STEP(T, QS)                                                        \
    {                                                                         \
        const bf16* at = at0 + (size_t)(T) * 8192;                            \
        _Pragma("unroll")                                                     \
        for (int kk = 0; kk < 2; kk++) {                                      \
            bf16x8 a0 = *(const bf16x8*)(at + aoff[0][kk]);                   \
            bf16x8 a1 = *(const bf16x8*)(at + aoff[1][kk]);                   \
            bf16x8 a2 = *(const bf16x8*)(at + aoff[2][kk]);                   \
            bf16x8 a3 = *(const bf16x8*)(at + aoff[3][kk]);                   \
            bf16x8 bv = *(const bf16x8*)&Bs[(T) & 1][swz(wn * 16 + lr, kk * 32 + lk)]; \
            acc[0] = __builtin_amdgcn_mfma_f32_16x16x32_bf16(a0, bv, acc[0], 0, 0, 0); \
            acc[1] = __builtin_amdgcn_mfma_f32_16x16x32_bf16(a1, bv, acc[1], 0, 0, 0); \
            acc[2] = __builtin_amdgcn_mfma_f32_16x16x32_bf16(a2, bv, acc[2], 0, 0, 0); \
            acc[3] = __builtin_amdgcn_mfma_f32_16x16x32_bf16(a3, bv, acc[3], 0, 0, 0); \
        }                                                                     \
        if ((T) + 1 < NT) {                                                   \
            WLDS(QS, ((T) + 1) & 1);                                          \
            if ((T) + 3 < NT) QST(QS, ((T) + 3) * 64);                        \
            if ((T) + 2 < NT) SZST(((T) + 2) * 64);                           \
            barrier_nodrain();                                                \
        }                                                                     \
    }

    QST(qa, 0);
    SZST(0);
    WLDS(qa, 0);
    QST(qa, 64);
    QST(qb, 128);
    SZST(64);
    barrier_nodrain();

    for (int t = 0; t < NT; t += 2) {
        GD_STEP(t, qa);
        GD_STEP(t + 1, qb);
    }
#undef QST
#undef SZST
#undef WLDS
#undef GD_STEP

    float* po = partials + (size_t)bz * T_DIM * H_DIM;
    const int orow = (lane >> 4) * 4;
#pragma unroll
    for (int mi = 0; mi < 4; mi++) {
#pragma unroll
        for (int r = 0; r < 4; r++) {
            int m = m0 + wm * 64 + mi * 16 + orow + r;
            int c = n0 + wn * 16 + lr;
            po[(size_t)m * H_DIM + c] = acc[mi][r];
        }
    }
}

// ---------------------------------------------------------------------------
template<int S>
__global__ void reduce_kernel(const float* __restrict__ partials, float* __restrict__ out) {
    size_t i = ((size_t)blockIdx.x * 256 + threadIdx.x) * 4;
    f32x4 a = *(const f32x4*)(partials + i);
#pragma unroll
    for (int s = 1; s < S; s++)
        a += *(const f32x4*)(partials + (size_t)s * T_DIM * H_DIM + i);
    *(f32x4*)(out + i) = a;
}

// ---------------------------------------------------------------------------
extern "C" void kernel_launch(void* const* d_in, const int* in_sizes, int n_in,
                              void* d_out, int out_size, void* d_ws, size_t ws_size,
                              hipStream_t stream) {
    const float* x   = (const float*)d_in[0];
    const int*   w1q = (const int*)d_in[1];
    const float* w1s = (const float*)d_in[2];
    const float* w1z = (const float*)d_in[3];
    const int*   w2q = (const int*)d_in[4];
    const float* w2s = (const float*)d_in[5];
    const float* w2z = (const float*)d_in[6];
    const int*   w3q = (const int*)d_in[7];
    const float* w3s = (const float*)d_in[8];
    const float* w3z = (const float*)d_in[9];

    bf16*  xb    = (bf16*)d_ws;                         // tiled [4][64][8192]
    bf16*  inter = xb + (size_t)T_DIM * H_DIM;          // tiled [4][224][8192]
    float* parts = (float*)(inter + (size_t)T_DIM * F_DIM);

    const size_t base   = (size_t)T_DIM * H_DIM * 2 + (size_t)T_DIM * F_DIM * 2;
    const size_t pbytes = (size_t)T_DIM * H_DIM * 4;

    cvt_x_kernel<<<dim3(2048), dim3(256), 0, stream>>>(x, xb);

    gemm_gateup<<<dim3(1792), dim3(256), 0, stream>>>(
        xb, w1q, w1s, w1z, w3q, w3s, w3z, inter);

    if (ws_size >= base + 4 * pbytes) {
        gemm_down<4><<<dim3(2048), dim3(256), 0, stream>>>(inter, w2q, w2s, w2z, parts);
        reduce_kernel<4><<<dim3(2048), dim3(256), 0, stream>>>(parts, (float*)d_out);
    } else if (ws_size >= base + 2 * pbytes) {
        gemm_down<2><<<dim3(1024), dim3(256), 0, stream>>>(inter, w2q, w2s, w2z, parts);
        reduce_kernel<2><<<dim3(2048), dim3(256), 0, stream>>>(parts, (float*)d_out);
    } else {
        gemm_down<1><<<dim3(512), dim3(256), 0, stream>>>(inter, w2q, w2s, w2z, parts);
        reduce_kernel<1><<<dim3(2048), dim3(256), 0, stream>>>(parts, (float*)d_out);
    }
}

// Round 13
// 627.191 us; speedup vs baseline: 2.4740x; 2.0838x over previous
//
#include <hip/hip_runtime.h>
#include <stdint.h>

typedef __bf16 bf16;
typedef __attribute__((ext_vector_type(8))) bf16 bf16x8;
typedef __attribute__((ext_vector_type(4))) bf16 bf16x4;
typedef __attribute__((ext_vector_type(4))) float f32x4;

#define T_DIM 512
#define H_DIM 4096
#define F_DIM 14336

// Tile = 128 rows x 64 cols bf16 = 16 KB, XOR-swizzled: elem = r*64 + (c ^ ((r&7)<<3)).
__device__ __forceinline__ int swz(int r, int c) {
    return r * 64 + (c ^ ((r & 7) << 3));
}

__device__ __forceinline__ int xcd_remap(int d, int chunk) {
    return (d & 7) * chunk + (d >> 3);
}

// Race-safe no-vmcnt-drain barrier (validated rounds 7/9/10).
__device__ __forceinline__ void barrier_nodrain() {
    __builtin_amdgcn_sched_barrier(0);
    asm volatile("s_waitcnt lgkmcnt(0)\n\ts_barrier" ::: "memory");
    __builtin_amdgcn_sched_barrier(0);
}

// ---------------------------------------------------------------------------
// x (f32 [512][4096]) -> xb tiled: [panel p=m>>7][ktile c>>6][swz(r,c) tile]
__global__ void cvt_x_kernel(const float* __restrict__ x, bf16* __restrict__ xbt) {
    int i = (blockIdx.x * 256 + threadIdx.x) * 4;
    int m = i >> 12;
    int c = i & 4095;
    float4 v = *(const float4*)(x + i);
    bf16x4 o = {(bf16)v.x, (bf16)v.y, (bf16)v.z, (bf16)v.w};
    int p = m >> 7, rm = m & 127, kt = c >> 6, kc = c & 63;
    *(bf16x4*)(xbt + (size_t)(p * 64 + kt) * 8192 + swz(rm, kc)) = o;
}

// ---------------------------------------------------------------------------
// Fused gate+up: inter = silu(x@W1^T) * (x@W3^T).
// EXACT round-9 structure minus the A-LDS path: A-frags read directly from
// tiled xb (L1/L2-hot; pattern verified r11/r12). B dequant -> dbuf LDS
// (16 KB total), 1-deep q/sz staging, one nodrain barrier per K-step.
__global__ __launch_bounds__(256, 3)
void gemm_gateup(const bf16* __restrict__ A,   // tiled xb
                 const int* __restrict__ Wq1, const float* __restrict__ Sc1,
                 const float* __restrict__ Zr1,
                 const int* __restrict__ Wq3, const float* __restrict__ Sc3,
                 const float* __restrict__ Zr3,
                 bf16* __restrict__ inter) {   // tiled output
    constexpr int KD = H_DIM;
    constexpr int NT = KD / 64;                    // 64
    __shared__ __align__(16) bf16 Bs1[2][32 * 64]; // 8 KB
    __shared__ __align__(16) bf16 Bs3[2][32 * 64]; // 8 KB

    const int l    = xcd_remap(blockIdx.x, 224);
    const int bx   = l & 3;                        // M panel (replicas co-XCD)
    const int by   = l >> 2;                       // N block 0..447
    const int tid  = threadIdx.x;
    const int lane = tid & 63;
    const int wid  = tid >> 6;
    const int wm   = wid >> 1, wn = wid & 1;
    const int lr   = lane & 15;
    const int lk   = (lane >> 4) * 8;
    const int n0   = by * 32;
    const int grp  = n0 >> 6;

    const int b_r = (tid >> 4) * 2;
    const int b_c = (tid & 15) * 4;

    const bf16* at0 = A + (size_t)bx * 64 * 8192;  // this panel's 64 ktiles

    f32x4 acc1[4], acc3[4];
    const f32x4 zf = {0.f, 0.f, 0.f, 0.f};
#pragma unroll
    for (int i = 0; i < 4; i++) { acc1[i] = zf; acc3[i] = zf; }

    int4   q1r[2], q3r[2];
    float4 s1r, z1r, s3r, z3r;

#define STAGE(K0)                                                                 \
    {                                                                             \
        _Pragma("unroll")                                                         \
        for (int i = 0; i < 2; i++) {                                             \
            q1r[i] = *(const int4*)(Wq1 + (size_t)(n0 + b_r + i) * KD + (K0) + b_c); \
            q3r[i] = *(const int4*)(Wq3 + (size_t)(n0 + b_r + i) * KD + (K0) + b_c); \
        }                                                                         \
        s1r = *(const float4*)(Sc1 + (size_t)grp * KD + (K0) + b_c);              \
        z1r = *(const float4*)(Zr1 + (size_t)grp * KD + (K0) + b_c);              \
        s3r = *(const float4*)(Sc3 + (size_t)grp * KD + (K0) + b_c);              \
        z3r = *(const float4*)(Zr3 + (size_t)grp * KD + (K0) + b_c);              \
    }

#define WLDS(nb)                                                                  \
    {                                                                             \
        float4 n1, n3;                                                            \
        n1.x = -z1r.x * s1r.x; n1.y = -z1r.y * s1r.y;                             \
        n1.z = -z1r.z * s1r.z; n1.w = -z1r.w * s1r.w;                             \
        n3.x = -z3r.x * s3r.x; n3.y = -z3r.y * s3r.y;                             \
        n3.z = -z3r.z * s3r.z; n3.w = -z3r.w * s3r.w;                             \
        _Pragma("unroll")                                                         \
        for (int i = 0; i < 2; i++) {                                             \
            bf16x4 v;                                                             \
            v[0] = (bf16)fmaf((float)q1r[i].x, s1r.x, n1.x);                      \
            v[1] = (bf16)fmaf((float)q1r[i].y, s1r.y, n1.y);                      \
            v[2] = (bf16)fmaf((float)q1r[i].z, s1r.z, n1.z);                      \
            v[3] = (bf16)fmaf((float)q1r[i].w, s1r.w, n1.w);                      \
            *(bf16x4*)&Bs1[nb][swz(b_r + i, b_c)] = v;                            \
            bf16x4 u;                                                             \
            u[0] = (bf16)fmaf((float)q3r[i].x, s3r.x, n3.x);                      \
            u[1] = (bf16)fmaf((float)q3r[i].y, s3r.y, n3.y);                      \
            u[2] = (bf16)fmaf((float)q3r[i].z, s3r.z, n3.z);                      \
            u[3] = (bf16)fmaf((float)q3r[i].w, s3r.w, n3.w);                      \
            *(bf16x4*)&Bs3[nb][swz(b_r + i, b_c)] = u;                            \
        }                                                                         \
    }

    // Prologue: W0 -> Bs[0]; W1 q/sz in flight across the barrier.
    STAGE(0);
    WLDS(0);
    STAGE(64);
    barrier_nodrain();

    for (int t = 0; t < NT; ++t) {
        const int cur = t & 1;
        const bf16* at = at0 + (size_t)t * 8192;
        // MFMA phase: A direct from global tile, B from LDS[cur].
#pragma unroll
        for (int kk = 0; kk < 2; kk++) {
            bf16x8 af[4], b1, b3;
#pragma unroll
            for (int mi = 0; mi < 4; mi++)
                af[mi] = *(const bf16x8*)(at + swz(wm * 64 + mi * 16 + lr, kk * 32 + lk));
            b1 = *(const bf16x8*)&Bs1[cur][swz(wn * 16 + lr, kk * 32 + lk)];
            b3 = *(const bf16x8*)&Bs3[cur][swz(wn * 16 + lr, kk * 32 + lk)];
#pragma unroll
            for (int mi = 0; mi < 4; mi++) {
                acc1[mi] = __builtin_amdgcn_mfma_f32_16x16x32_bf16(af[mi], b1, acc1[mi], 0, 0, 0);
                acc3[mi] = __builtin_amdgcn_mfma_f32_16x16x32_bf16(af[mi], b3, acc3[mi], 0, 0, 0);
            }
        }
        // Stage phase: dequant tile t+1 (regs staged in step t-1), issue t+2.
        if (t + 1 < NT) {
            WLDS(cur ^ 1);
            if (t + 2 < NT) STAGE((t + 2) * 64);
            barrier_nodrain();        // lgkmcnt(0) only — global loads cross
        }
    }
#undef STAGE
#undef WLDS

    // Epilogue: silu(gate)*up -> tiled inter (verified r10/r11/r12).
    const int orow = (lane >> 4) * 4;
    const int cg   = n0 + wn * 16 + lr;
    const int kt   = cg >> 6, kc = cg & 63;
    bf16* itile = inter + (size_t)(bx * 224 + kt) * 8192;
#pragma unroll
    for (int mi = 0; mi < 4; mi++) {
#pragma unroll
        for (int r = 0; r < 4; r++) {
            int rm = wm * 64 + mi * 16 + orow + r;
            float g = acc1[mi][r];
            float u = acc3[mi][r];
            float s = g / (1.0f + __expf(-g));
            itile[swz(rm, kc)] = (bf16)(s * u);
        }
    }
}

// ---------------------------------------------------------------------------
// Down proj, split-K: same r9 structure minus A-LDS; A direct from tiled inter.
template<int SPLITK>
__global__ __launch_bounds__(256, 4)
void gemm_down(const bf16* __restrict__ A,    // tiled inter
               const int* __restrict__ Wq,
               const float* __restrict__ Sc, const float* __restrict__ Zr,
               float* __restrict__ partials) {
    constexpr int KD = F_DIM;
    constexpr int KC = KD / SPLITK;
    constexpr int NT = KC / 64;                    // 56 (even)
    __shared__ __align__(16) bf16 Bs[2][32 * 64];  // 8 KB

    const int l    = xcd_remap(blockIdx.x, 64 * SPLITK);
    const int bx   = l & 3;
    const int by   = (l >> 2) & 127;
    const int bz   = l >> 9;
    const int tid  = threadIdx.x;
    const int lane = tid & 63;
    const int wid  = tid >> 6;
    const int wm   = wid >> 1, wn = wid & 1;
    const int lr   = lane & 15;
    const int lk   = (lane >> 4) * 8;
    const int m0   = bx * 128;
    const int n0   = by * 32;
    const int grp  = n0 >> 6;
    const int kbeg = bz * KC;

    const int b_r = (tid >> 4) * 2;
    const int b_c = (tid & 15) * 4;

    const bf16* at0 = A + (size_t)(bx * 224 + bz * NT) * 8192;

    f32x4 acc[4];
    const f32x4 zf = {0.f, 0.f, 0.f, 0.f};
#pragma unroll
    for (int i = 0; i < 4; i++) acc[i] = zf;

    int4   qr[2];
    float4 sr, zr;

#define STAGE(K0)                                                                 \
    {                                                                             \
        _Pragma("unroll")                                                         \
        for (int i = 0; i < 2; i++)                                               \
            qr[i] = *(const int4*)(Wq + (size_t)(n0 + b_r + i) * KD + kbeg + (K0) + b_c); \
        sr = *(const float4*)(Sc + (size_t)grp * KD + kbeg + (K0) + b_c);         \
        zr = *(const float4*)(Zr + (size_t)grp * KD + kbeg + (K0) + b_c);         \
    }

#define WLDS(nb)                                                                  \
    {                                                                             \
        float4 nz;                                                                \
        nz.x = -zr.x * sr.x; nz.y = -zr.y * sr.y;                                 \
        nz.z = -zr.z * sr.z; nz.w = -zr.w * sr.w;                                 \
        _Pragma("unroll")                                                         \
        for (int i = 0; i < 2; i++) {                                             \
            bf16x4 v;                                                             \
            v[0] = (bf16)fmaf((float)qr[i].x, sr.x, nz.x);                        \
            v[1] = (bf16)fmaf((float)qr[i].y, sr.y, nz.y);                        \
            v[2] = (bf16)fmaf((float)qr[i].z, sr.z, nz.z);                        \
            v[3] = (bf16)fmaf((float)qr[i].w, sr.w, nz.w);                        \
            *(bf16x4*)&Bs[nb][swz(b_r + i, b_c)] = v;                             \
        }                                                                         \
    }

    STAGE(0);
    WLDS(0);
    STAGE(64);
    barrier_nodrain();

    for (int t = 0; t < NT; ++t) {
        const int cur = t & 1;
        const bf16* at = at0 + (size_t)t * 8192;
#pragma unroll
        for (int kk = 0; kk < 2; kk++) {
            bf16x8 af[4], bv;
#pragma unroll
            for (int mi = 0; mi < 4; mi++)
                af[mi] = *(const bf16x8*)(at + swz(wm * 64 + mi * 16 + lr, kk * 32 + lk));
            bv = *(const bf16x8*)&Bs[cur][swz(wn * 16 + lr, kk * 32 + lk)];
#pragma unroll
            for (int mi = 0; mi < 4; mi++)
                acc[mi] = __builtin_amdgcn_mfma_f32_16x16x32_bf16(af[mi], bv, acc[mi], 0, 0, 0);
        }
        if (t + 1 < NT) {
            WLDS(cur ^ 1);
            if (t + 2 < NT) STAGE((t + 2) * 64);
            barrier_nodrain();
        }
    }
#undef STAGE
#undef WLDS

    float* po = partials + (size_t)bz * T_DIM * H_DIM;
    const int orow = (lane >> 4) * 4;
#pragma unroll
    for (int mi = 0; mi < 4; mi++) {
#pragma unroll
        for (int r = 0; r < 4; r++) {
            int m = m0 + wm * 64 + mi * 16 + orow + r;
            int c = n0 + wn * 16 + lr;
            po[(size_t)m * H_DIM + c] = acc[mi][r];
        }
    }
}

// ---------------------------------------------------------------------------
template<int S>
__global__ void reduce_kernel(const float* __restrict__ partials, float* __restrict__ out) {
    size_t i = ((size_t)blockIdx.x * 256 + threadIdx.x) * 4;
    f32x4 a = *(const f32x4*)(partials + i);
#pragma unroll
    for (int s = 1; s < S; s++)
        a += *(const f32x4*)(partials + (size_t)s * T_DIM * H_DIM + i);
    *(f32x4*)(out + i) = a;
}

// ---------------------------------------------------------------------------
extern "C" void kernel_launch(void* const* d_in, const int* in_sizes, int n_in,
                              void* d_out, int out_size, void* d_ws, size_t ws_size,
                              hipStream_t stream) {
    const float* x   = (const float*)d_in[0];
    const int*   w1q = (const int*)d_in[1];
    const float* w1s = (const float*)d_in[2];
    const float* w1z = (const float*)d_in[3];
    const int*   w2q = (const int*)d_in[4];
    const float* w2s = (const float*)d_in[5];
    const float* w2z = (const float*)d_in[6];
    const int*   w3q = (const int*)d_in[7];
    const float* w3s = (const float*)d_in[8];
    const float* w3z = (const float*)d_in[9];

    bf16*  xb    = (bf16*)d_ws;                         // tiled [4][64][8192]
    bf16*  inter = xb + (size_t)T_DIM * H_DIM;          // tiled [4][224][8192]
    float* parts = (float*)(inter + (size_t)T_DIM * F_DIM);

    const size_t base   = (size_t)T_DIM * H_DIM * 2 + (size_t)T_DIM * F_DIM * 2;
    const size_t pbytes = (size_t)T_DIM * H_DIM * 4;

    cvt_x_kernel<<<dim3(2048), dim3(256), 0, stream>>>(x, xb);

    gemm_gateup<<<dim3(1792), dim3(256), 0, stream>>>(
        xb, w1q, w1s, w1z, w3q, w3s, w3z, inter);

    if (ws_size >= base + 4 * pbytes) {
        gemm_down<4><<<dim3(2048), dim3(256), 0, stream>>>(inter, w2q, w2s, w2z, parts);
        reduce_kernel<4><<<dim3(2048), dim3(256), 0, stream>>>(parts, (float*)d_out);
    } else if (ws_size >= base + 2 * pbytes) {
        gemm_down<2><<<dim3(1024), dim3(256), 0, stream>>>(inter, w2q, w2s, w2z, parts);
        reduce_kernel<2><<<dim3(2048), dim3(256), 0, stream>>>(parts, (float*)d_out);
    } else {
        gemm_down<1><<<dim3(512), dim3(256), 0, stream>>>(inter, w2q, w2s, w2z, parts);
        reduce_kernel<1><<<dim3(2048), dim3(256), 0, stream>>>(parts, (float*)d_out);
    }
}

// Round 14
// 381.439 us; speedup vs baseline: 4.0680x; 1.6443x over previous
//
#include <hip/hip_runtime.h>
#include <stdint.h>

typedef __bf16 bf16;
typedef __attribute__((ext_vector_type(8))) bf16 bf16x8;
typedef __attribute__((ext_vector_type(4))) bf16 bf16x4;
typedef __attribute__((ext_vector_type(4))) float f32x4;

#define T_DIM 512
#define H_DIM 4096
#define F_DIM 14336

// LDS tiles: [rows][64] bf16, XOR-swizzled: elem = r*64 + (c ^ ((r&7)<<3)).
__device__ __forceinline__ int swz(int r, int c) {
    return r * 64 + (c ^ ((r & 7) << 3));
}

__device__ __forceinline__ int xcd_remap(int d, int chunk) {
    return (d & 7) * chunk + (d >> 3);
}

// Race-safe no-vmcnt-drain barrier (validated rounds 7/9/10/13).
__device__ __forceinline__ void barrier_nodrain() {
    __builtin_amdgcn_sched_barrier(0);
    asm volatile("s_waitcnt lgkmcnt(0)\n\ts_barrier" ::: "memory");
    __builtin_amdgcn_sched_barrier(0);
}

// ---------------------------------------------------------------------------
__global__ void cvt_x_kernel(const float* __restrict__ x, bf16* __restrict__ xb) {
    int i = (blockIdx.x * 256 + threadIdx.x) * 4;
    float4 v = *(const float4*)(x + i);
    bf16x4 o = {(bf16)v.x, (bf16)v.y, (bf16)v.z, (bf16)v.w};
    *(bf16x4*)(xb + i) = o;
}

// ---------------------------------------------------------------------------
// Fused gate+up: inter = silu(x@W1^T) * (x@W3^T).
// Tile 128(M) x 64(N), BK=64, 4 waves (2M x 2N, wave-tile 64x32).
// r9 pipeline verbatim: dbuf LDS, reg-staged A+W (1-deep), one nodrain
// barrier per K-step. vs r9: N doubled -> LDS-read bytes per MFMA halved
// (LDS port was the most-utilized resource), 32 MFMA per barrier interval.
__global__ __launch_bounds__(256, 2)
void gemm_gateup(const bf16* __restrict__ A,
                 const int* __restrict__ Wq1, const float* __restrict__ Sc1,
                 const float* __restrict__ Zr1,
                 const int* __restrict__ Wq3, const float* __restrict__ Sc3,
                 const float* __restrict__ Zr3,
                 bf16* __restrict__ inter) {
    constexpr int KD = H_DIM;
    constexpr int NT = KD / 64;                     // 64 (even)
    __shared__ __align__(16) bf16 As[2][128 * 64];  // 32 KB
    __shared__ __align__(16) bf16 Bs1[2][64 * 64];  // 16 KB
    __shared__ __align__(16) bf16 Bs3[2][64 * 64];  // 16 KB

    const int l    = xcd_remap(blockIdx.x, 112);    // 896/8
    const int bx   = l & 3;                         // M panel (replicas co-XCD)
    const int by   = l >> 2;                        // N block 0..223
    const int tid  = threadIdx.x;
    const int lane = tid & 63;
    const int wid  = tid >> 6;
    const int wm   = wid >> 1, wn = wid & 1;
    const int lr   = lane & 15;
    const int lk   = (lane >> 4) * 8;
    const int m0   = bx * 128;
    const int n0   = by * 64;
    const int grp  = by;                            // HQQ group (64-aligned)

    // A staging: rows {tid>>2, +64} x col-chunks {(tid&3)*8, +32}
    const int a_r = tid >> 2;
    const int a_c = (tid & 3) * 8;
    // B staging: rows (tid>>4)*4 .. +3, cols (tid&15)*4 .. +3 (per weight)
    const int b_r = (tid >> 4) * 4;
    const int b_c = (tid & 15) * 4;

    f32x4 acc1[4][2], acc3[4][2];
    const f32x4 zf = {0.f, 0.f, 0.f, 0.f};
#pragma unroll
    for (int i = 0; i < 4; i++)
#pragma unroll
        for (int j = 0; j < 2; j++) { acc1[i][j] = zf; acc3[i][j] = zf; }

    bf16x8 areg[4];
    int4   q1r[4], q3r[4];
    float4 s1r, z1r, s3r, z3r;

#define STAGE(K0)                                                                 \
    {                                                                             \
        _Pragma("unroll")                                                         \
        for (int p = 0; p < 2; p++)                                               \
            _Pragma("unroll")                                                     \
            for (int h = 0; h < 2; h++)                                           \
                areg[p * 2 + h] = *(const bf16x8*)(A + (size_t)(m0 + a_r + 64 * p) * KD + (K0) + a_c + 32 * h); \
        _Pragma("unroll")                                                         \
        for (int i = 0; i < 4; i++) {                                             \
            q1r[i] = *(const int4*)(Wq1 + (size_t)(n0 + b_r + i) * KD + (K0) + b_c); \
            q3r[i] = *(const int4*)(Wq3 + (size_t)(n0 + b_r + i) * KD + (K0) + b_c); \
        }                                                                         \
        s1r = *(const float4*)(Sc1 + (size_t)grp * KD + (K0) + b_c);              \
        z1r = *(const float4*)(Zr1 + (size_t)grp * KD + (K0) + b_c);              \
        s3r = *(const float4*)(Sc3 + (size_t)grp * KD + (K0) + b_c);              \
        z3r = *(const float4*)(Zr3 + (size_t)grp * KD + (K0) + b_c);              \
    }

#define WLDS(nb)                                                                  \
    {                                                                             \
        _Pragma("unroll")                                                         \
        for (int p = 0; p < 2; p++)                                               \
            _Pragma("unroll")                                                     \
            for (int h = 0; h < 2; h++)                                           \
                *(bf16x8*)&As[nb][swz(a_r + 64 * p, a_c + 32 * h)] = areg[p * 2 + h]; \
        float4 n1, n3;                                                            \
        n1.x = -z1r.x * s1r.x; n1.y = -z1r.y * s1r.y;                             \
        n1.z = -z1r.z * s1r.z; n1.w = -z1r.w * s1r.w;                             \
        n3.x = -z3r.x * s3r.x; n3.y = -z3r.y * s3r.y;                             \
        n3.z = -z3r.z * s3r.z; n3.w = -z3r.w * s3r.w;                             \
        _Pragma("unroll")                                                         \
        for (int i = 0; i < 4; i++) {                                             \
            bf16x4 v;                                                             \
            v[0] = (bf16)fmaf((float)q1r[i].x, s1r.x, n1.x);                      \
            v[1] = (bf16)fmaf((float)q1r[i].y, s1r.y, n1.y);                      \
            v[2] = (bf16)fmaf((float)q1r[i].z, s1r.z, n1.z);                      \
            v[3] = (bf16)fmaf((float)q1r[i].w, s1r.w, n1.w);                      \
            *(bf16x4*)&Bs1[nb][swz(b_r + i, b_c)] = v;                            \
            bf16x4 u;                                                             \
            u[0] = (bf16)fmaf((float)q3r[i].x, s3r.x, n3.x);                      \
            u[1] = (bf16)fmaf((float)q3r[i].y, s3r.y, n3.y);                      \
            u[2] = (bf16)fmaf((float)q3r[i].z, s3r.z, n3.z);                      \
            u[3] = (bf16)fmaf((float)q3r[i].w, s3r.w, n3.w);                      \
            *(bf16x4*)&Bs3[nb][swz(b_r + i, b_c)] = u;                            \
        }                                                                         \
    }

    // Prologue: tile0 -> LDS[0]; tile1 loads in flight across the barrier.
    STAGE(0);
    WLDS(0);
    STAGE(64);
    barrier_nodrain();

    for (int t = 0; t < NT; ++t) {
        const int cur = t & 1;
        // MFMA phase: 32 MFMA on LDS[cur]; next tile's loads still in flight.
#pragma unroll
        for (int kk = 0; kk < 2; kk++) {
            bf16x8 af[4], b1[2], b3[2];
#pragma unroll
            for (int mi = 0; mi < 4; mi++)
                af[mi] = *(const bf16x8*)&As[cur][swz(wm * 64 + mi * 16 + lr, kk * 32 + lk)];
#pragma unroll
            for (int ni = 0; ni < 2; ni++) {
                b1[ni] = *(const bf16x8*)&Bs1[cur][swz(wn * 32 + ni * 16 + lr, kk * 32 + lk)];
                b3[ni] = *(const bf16x8*)&Bs3[cur][swz(wn * 32 + ni * 16 + lr, kk * 32 + lk)];
            }
#pragma unroll
            for (int mi = 0; mi < 4; mi++)
#pragma unroll
                for (int ni = 0; ni < 2; ni++) {
                    acc1[mi][ni] = __builtin_amdgcn_mfma_f32_16x16x32_bf16(af[mi], b1[ni], acc1[mi][ni], 0, 0, 0);
                    acc3[mi][ni] = __builtin_amdgcn_mfma_f32_16x16x32_bf16(af[mi], b3[ni], acc3[mi][ni], 0, 0, 0);
                }
        }
        // Stage phase: write tile t+1 (regs staged step t-1), issue t+2.
        if (t + 1 < NT) {
            WLDS(cur ^ 1);
            if (t + 2 < NT) STAGE((t + 2) * 64);
            barrier_nodrain();        // lgkmcnt(0) only — loads cross freely
        }
    }
#undef STAGE
#undef WLDS

    // Epilogue: silu(gate)*up -> inter (row-major).
    const int orow = (lane >> 4) * 4;
#pragma unroll
    for (int mi = 0; mi < 4; mi++)
#pragma unroll
        for (int ni = 0; ni < 2; ni++) {
#pragma unroll
            for (int r = 0; r < 4; r++) {
                int m = m0 + wm * 64 + mi * 16 + orow + r;
                int c = n0 + wn * 32 + ni * 16 + lr;
                float g = acc1[mi][ni][r];
                float u = acc3[mi][ni][r];
                float s = g / (1.0f + __expf(-g));
                inter[(size_t)m * F_DIM + c] = (bf16)(s * u);
            }
        }
}

// ---------------------------------------------------------------------------
// Down proj, split-K: tile 128x64, wave 64x32, same pipeline.
// grid = 4 * 64 * SPLITK (1-D XCD-remapped).
template<int SPLITK>
__global__ __launch_bounds__(256, 3)
void gemm_down(const bf16* __restrict__ A, const int* __restrict__ Wq,
               const float* __restrict__ Sc, const float* __restrict__ Zr,
               float* __restrict__ partials) {
    constexpr int KD = F_DIM;
    constexpr int KC = KD / SPLITK;
    constexpr int NT = KC / 64;                     // 56 (even)
    __shared__ __align__(16) bf16 As[2][128 * 64];  // 32 KB
    __shared__ __align__(16) bf16 Bs[2][64 * 64];   // 16 KB

    const int l    = xcd_remap(blockIdx.x, 32 * SPLITK);  // (4*64*SK)/8
    const int bx   = l & 3;
    const int by   = (l >> 2) & 63;
    const int bz   = l >> 8;
    const int tid  = threadIdx.x;
    const int lane = tid & 63;
    const int wid  = tid >> 6;
    const int wm   = wid >> 1, wn = wid & 1;
    const int lr   = lane & 15;
    const int lk   = (lane >> 4) * 8;
    const int m0   = bx * 128;
    const int n0   = by * 64;
    const int grp  = by;
    const int kbeg = bz * KC;

    const int a_r = tid >> 2;
    const int a_c = (tid & 3) * 8;
    const int b_r = (tid >> 4) * 4;
    const int b_c = (tid & 15) * 4;

    f32x4 acc[4][2];
    const f32x4 zf = {0.f, 0.f, 0.f, 0.f};
#pragma unroll
    for (int i = 0; i < 4; i++)
#pragma unroll
        for (int j = 0; j < 2; j++) acc[i][j] = zf;

    bf16x8 areg[4];
    int4   qr[4];
    float4 sr, zr;

#define STAGE(K0)                                                                 \
    {                                                                             \
        _Pragma("unroll")                                                         \
        for (int p = 0; p < 2; p++)                                               \
            _Pragma("unroll")                                                     \
            for (int h = 0; h < 2; h++)                                           \
                areg[p * 2 + h] = *(const bf16x8*)(A + (size_t)(m0 + a_r + 64 * p) * KD + kbeg + (K0) + a_c + 32 * h); \
        _Pragma("unroll")                                                         \
        for (int i = 0; i < 4; i++)                                               \
            qr[i] = *(const int4*)(Wq + (size_t)(n0 + b_r + i) * KD + kbeg + (K0) + b_c); \
        sr = *(const float4*)(Sc + (size_t)grp * KD + kbeg + (K0) + b_c);         \
        zr = *(const float4*)(Zr + (size_t)grp * KD + kbeg + (K0) + b_c);         \
    }

#define WLDS(nb)                                                                  \
    {                                                                             \
        _Pragma("unroll")                                                         \
        for (int p = 0; p < 2; p++)                                               \
            _Pragma("unroll")                                                     \
            for (int h = 0; h < 2; h++)                                           \
                *(bf16x8*)&As[nb][swz(a_r + 64 * p, a_c + 32 * h)] = areg[p * 2 + h]; \
        float4 nz;                                                                \
        nz.x = -zr.x * sr.x; nz.y = -zr.y * sr.y;                                 \
        nz.z = -zr.z * sr.z; nz.w = -zr.w * sr.w;                                 \
        _Pragma("unroll")                                                         \
        for (int i = 0; i < 4; i++) {                                             \
            bf16x4 v;                                                             \
            v[0] = (bf16)fmaf((float)qr[i].x, sr.x, nz.x);                        \
            v[1] = (bf16)fmaf((float)qr[i].y, sr.y, nz.y);                        \
            v[2] = (bf16)fmaf((float)qr[i].z, sr.z, nz.z);                        \
            v[3] = (bf16)fmaf((float)qr[i].w, sr.w, nz.w);                        \
            *(bf16x4*)&Bs[nb][swz(b_r + i, b_c)] = v;                             \
        }                                                                         \
    }

    STAGE(0);
    WLDS(0);
    STAGE(64);
    barrier_nodrain();

    for (int t = 0; t < NT; ++t) {
        const int cur = t & 1;
#pragma unroll
        for (int kk = 0; kk < 2; kk++) {
            bf16x8 af[4], bfr[2];
#pragma unroll
            for (int mi = 0; mi < 4; mi++)
                af[mi] = *(const bf16x8*)&As[cur][swz(wm * 64 + mi * 16 + lr, kk * 32 + lk)];
#pragma unroll
            for (int ni = 0; ni < 2; ni++)
                bfr[ni] = *(const bf16x8*)&Bs[cur][swz(wn * 32 + ni * 16 + lr, kk * 32 + lk)];
#pragma unroll
            for (int mi = 0; mi < 4; mi++)
#pragma unroll
                for (int ni = 0; ni < 2; ni++)
                    acc[mi][ni] = __builtin_amdgcn_mfma_f32_16x16x32_bf16(af[mi], bfr[ni], acc[mi][ni], 0, 0, 0);
        }
        if (t + 1 < NT) {
            WLDS(cur ^ 1);
            if (t + 2 < NT) STAGE((t + 2) * 64);
            barrier_nodrain();
        }
    }
#undef STAGE
#undef WLDS

    float* po = partials + (size_t)bz * T_DIM * H_DIM;
    const int orow = (lane >> 4) * 4;
#pragma unroll
    for (int mi = 0; mi < 4; mi++)
#pragma unroll
        for (int ni = 0; ni < 2; ni++) {
#pragma unroll
            for (int r = 0; r < 4; r++) {
                int m = m0 + wm * 64 + mi * 16 + orow + r;
                int c = n0 + wn * 32 + ni * 16 + lr;
                po[(size_t)m * H_DIM + c] = acc[mi][ni][r];
            }
        }
}

// ---------------------------------------------------------------------------
template<int S>
__global__ void reduce_kernel(const float* __restrict__ partials, float* __restrict__ out) {
    size_t i = ((size_t)blockIdx.x * 256 + threadIdx.x) * 4;
    f32x4 a = *(const f32x4*)(partials + i);
#pragma unroll
    for (int s = 1; s < S; s++)
        a += *(const f32x4*)(partials + (size_t)s * T_DIM * H_DIM + i);
    *(f32x4*)(out + i) = a;
}

// ---------------------------------------------------------------------------
extern "C" void kernel_launch(void* const* d_in, const int* in_sizes, int n_in,
                              void* d_out, int out_size, void* d_ws, size_t ws_size,
                              hipStream_t stream) {
    const float* x   = (const float*)d_in[0];
    const int*   w1q = (const int*)d_in[1];
    const float* w1s = (const float*)d_in[2];
    const float* w1z = (const float*)d_in[3];
    const int*   w2q = (const int*)d_in[4];
    const float* w2s = (const float*)d_in[5];
    const float* w2z = (const float*)d_in[6];
    const int*   w3q = (const int*)d_in[7];
    const float* w3s = (const float*)d_in[8];
    const float* w3z = (const float*)d_in[9];

    bf16*  xb    = (bf16*)d_ws;                         // [512][4096]  bf16
    bf16*  inter = xb + (size_t)T_DIM * H_DIM;          // [512][14336] bf16
    float* parts = (float*)(inter + (size_t)T_DIM * F_DIM);

    const size_t base   = (size_t)T_DIM * H_DIM * 2 + (size_t)T_DIM * F_DIM * 2;
    const size_t pbytes = (size_t)T_DIM * H_DIM * 4;

    cvt_x_kernel<<<dim3(2048), dim3(256), 0, stream>>>(x, xb);

    // gateup: (M/128=4) x (F/64=224) = 896 blocks, 1-D XCD-remapped
    gemm_gateup<<<dim3(896), dim3(256), 0, stream>>>(
        xb, w1q, w1s, w1z, w3q, w3s, w3z, inter);

    if (ws_size >= base + 4 * pbytes) {
        gemm_down<4><<<dim3(1024), dim3(256), 0, stream>>>(inter, w2q, w2s, w2z, parts);
        reduce_kernel<4><<<dim3(2048), dim3(256), 0, stream>>>(parts, (float*)d_out);
    } else if (ws_size >= base + 2 * pbytes) {
        gemm_down<2><<<dim3(512), dim3(256), 0, stream>>>(inter, w2q, w2s, w2z, parts);
        reduce_kernel<2><<<dim3(2048), dim3(256), 0, stream>>>(parts, (float*)d_out);
    } else {
        gemm_down<1><<<dim3(256), dim3(256), 0, stream>>>(inter, w2q, w2s, w2z, parts);
        reduce_kernel<1><<<dim3(2048), dim3(256), 0, stream>>>(parts, (float*)d_out);
    }
}

// Round 15
// 381.315 us; speedup vs baseline: 4.0693x; 1.0003x over previous
//
#include <hip/hip_runtime.h>
#include <stdint.h>

typedef __bf16 bf16;
typedef __attribute__((ext_vector_type(8))) bf16 bf16x8;
typedef __attribute__((ext_vector_type(4))) bf16 bf16x4;
typedef __attribute__((ext_vector_type(4))) float f32x4;

#define T_DIM 512
#define H_DIM 4096
#define F_DIM 14336

// LDS tiles: [rows][64] bf16, XOR-swizzled: elem = r*64 + (c ^ ((r&7)<<3)).
__device__ __forceinline__ int swz(int r, int c) {
    return r * 64 + (c ^ ((r & 7) << 3));
}

__device__ __forceinline__ int xcd_remap(int d, int chunk) {
    return (d & 7) * chunk + (d >> 3);
}

// Race-safe no-vmcnt-drain barrier (validated rounds 7/9/10/13/14).
__device__ __forceinline__ void barrier_nodrain() {
    __builtin_amdgcn_sched_barrier(0);
    asm volatile("s_waitcnt lgkmcnt(0)\n\ts_barrier" ::: "memory");
    __builtin_amdgcn_sched_barrier(0);
}

// ---------------------------------------------------------------------------
__global__ void cvt_x_kernel(const float* __restrict__ x, bf16* __restrict__ xb) {
    int i = (blockIdx.x * 256 + threadIdx.x) * 4;
    float4 v = *(const float4*)(x + i);
    bf16x4 o = {(bf16)v.x, (bf16)v.y, (bf16)v.z, (bf16)v.w};
    *(bf16x4*)(xb + i) = o;
}

// ---------------------------------------------------------------------------
// Fused gate+up: inter = silu(x@W1^T) * (x@W3^T).
// r14 structure (tile 128x64, wave 64x32, dbuf LDS, nodrain barrier) with the
// q weight staging DOUBLED (qa=even tiles, qb=odd): each set is refilled with
// W(t+3) right after WLDS(t+1) consumes it -> q flight ~2 steps > HBM latency.
// A (L2-hot) and s/z (small) stay 1-deep.
__global__ __launch_bounds__(256, 2)
void gemm_gateup(const bf16* __restrict__ A,
                 const int* __restrict__ Wq1, const float* __restrict__ Sc1,
                 const float* __restrict__ Zr1,
                 const int* __restrict__ Wq3, const float* __restrict__ Sc3,
                 const float* __restrict__ Zr3,
                 bf16* __restrict__ inter) {
    constexpr int KD = H_DIM;
    constexpr int NT = KD / 64;                     // 64 (even)
    __shared__ __align__(16) bf16 As[2][128 * 64];  // 32 KB
    __shared__ __align__(16) bf16 Bs1[2][64 * 64];  // 16 KB
    __shared__ __align__(16) bf16 Bs3[2][64 * 64];  // 16 KB

    const int l    = xcd_remap(blockIdx.x, 112);    // 896/8
    const int bx   = l & 3;
    const int by   = l >> 2;
    const int tid  = threadIdx.x;
    const int lane = tid & 63;
    const int wid  = tid >> 6;
    const int wm   = wid >> 1, wn = wid & 1;
    const int lr   = lane & 15;
    const int lk   = (lane >> 4) * 8;
    const int m0   = bx * 128;
    const int n0   = by * 64;
    const int grp  = by;

    const int a_r = tid >> 2;
    const int a_c = (tid & 3) * 8;
    const int b_r = (tid >> 4) * 4;
    const int b_c = (tid & 15) * 4;

    f32x4 acc1[4][2], acc3[4][2];
    const f32x4 zf = {0.f, 0.f, 0.f, 0.f};
#pragma unroll
    for (int i = 0; i < 4; i++)
#pragma unroll
        for (int j = 0; j < 2; j++) { acc1[i][j] = zf; acc3[i][j] = zf; }

    bf16x8 areg[4];
    int4   qa1[4], qa3[4];     // q set A (even tiles)
    int4   qb1[4], qb3[4];     // q set B (odd tiles)
    float4 s1r, z1r, s3r, z3r;

#define ASZ(K0)                                                                   \
    {                                                                             \
        _Pragma("unroll")                                                         \
        for (int p = 0; p < 2; p++)                                               \
            _Pragma("unroll")                                                     \
            for (int h = 0; h < 2; h++)                                           \
                areg[p * 2 + h] = *(const bf16x8*)(A + (size_t)(m0 + a_r + 64 * p) * KD + (K0) + a_c + 32 * h); \
        s1r = *(const float4*)(Sc1 + (size_t)grp * KD + (K0) + b_c);              \
        z1r = *(const float4*)(Zr1 + (size_t)grp * KD + (K0) + b_c);              \
        s3r = *(const float4*)(Sc3 + (size_t)grp * KD + (K0) + b_c);              \
        z3r = *(const float4*)(Zr3 + (size_t)grp * KD + (K0) + b_c);              \
    }

#define QST(Q1, Q3, K0)                                                           \
    {                                                                             \
        _Pragma("unroll")                                                         \
        for (int i = 0; i < 4; i++) {                                             \
            Q1[i] = *(const int4*)(Wq1 + (size_t)(n0 + b_r + i) * KD + (K0) + b_c); \
            Q3[i] = *(const int4*)(Wq3 + (size_t)(n0 + b_r + i) * KD + (K0) + b_c); \
        }                                                                         \
    }

#define WLDS(Q1, Q3, nb)                                                          \
    {                                                                             \
        _Pragma("unroll")                                                         \
        for (int p = 0; p < 2; p++)                                               \
            _Pragma("unroll")                                                     \
            for (int h = 0; h < 2; h++)                                           \
                *(bf16x8*)&As[nb][swz(a_r + 64 * p, a_c + 32 * h)] = areg[p * 2 + h]; \
        float4 n1, n3;                                                            \
        n1.x = -z1r.x * s1r.x; n1.y = -z1r.y * s1r.y;                             \
        n1.z = -z1r.z * s1r.z; n1.w = -z1r.w * s1r.w;                             \
        n3.x = -z3r.x * s3r.x; n3.y = -z3r.y * s3r.y;                             \
        n3.z = -z3r.z * s3r.z; n3.w = -z3r.w * s3r.w;                             \
        _Pragma("unroll")                                                         \
        for (int i = 0; i < 4; i++) {                                             \
            bf16x4 v;                                                             \
            v[0] = (bf16)fmaf((float)Q1[i].x, s1r.x, n1.x);                       \
            v[1] = (bf16)fmaf((float)Q1[i].y, s1r.y, n1.y);                       \
            v[2] = (bf16)fmaf((float)Q1[i].z, s1r.z, n1.z);                       \
            v[3] = (bf16)fmaf((float)Q1[i].w, s1r.w, n1.w);                       \
            *(bf16x4*)&Bs1[nb][swz(b_r + i, b_c)] = v;                            \
            bf16x4 u;                                                             \
            u[0] = (bf16)fmaf((float)Q3[i].x, s3r.x, n3.x);                       \
            u[1] = (bf16)fmaf((float)Q3[i].y, s3r.y, n3.y);                       \
            u[2] = (bf16)fmaf((float)Q3[i].z, s3r.z, n3.z);                       \
            u[3] = (bf16)fmaf((float)Q3[i].w, s3r.w, n3.w);                       \
            *(bf16x4*)&Bs3[nb][swz(b_r + i, b_c)] = u;                            \
        }                                                                         \
    }

#define MFMA_PH(nb)                                                               \
    {                                                                             \
        _Pragma("unroll")                                                         \
        for (int kk = 0; kk < 2; kk++) {                                          \
            bf16x8 af[4], b1[2], b3[2];                                           \
            _Pragma("unroll")                                                     \
            for (int mi = 0; mi < 4; mi++)                                        \
                af[mi] = *(const bf16x8*)&As[nb][swz(wm * 64 + mi * 16 + lr, kk * 32 + lk)]; \
            _Pragma("unroll")                                                     \
            for (int ni = 0; ni < 2; ni++) {                                      \
                b1[ni] = *(const bf16x8*)&Bs1[nb][swz(wn * 32 + ni * 16 + lr, kk * 32 + lk)]; \
                b3[ni] = *(const bf16x8*)&Bs3[nb][swz(wn * 32 + ni * 16 + lr, kk * 32 + lk)]; \
            }                                                                     \
            _Pragma("unroll")                                                     \
            for (int mi = 0; mi < 4; mi++)                                        \
                _Pragma("unroll")                                                 \
                for (int ni = 0; ni < 2; ni++) {                                  \
                    acc1[mi][ni] = __builtin_amdgcn_mfma_f32_16x16x32_bf16(af[mi], b1[ni], acc1[mi][ni], 0, 0, 0); \
                    acc3[mi][ni] = __builtin_amdgcn_mfma_f32_16x16x32_bf16(af[mi], b3[ni], acc3[mi][ni], 0, 0, 0); \
                }                                                                 \
        }                                                                         \
    }

    // Prologue: W0(qa)+A0 -> LDS[0]; qb=W1, qa=W2 in flight; A1/sz1 staged.
    ASZ(0);
    QST(qa1, qa3, 0);
    WLDS(qa1, qa3, 0);
    ASZ(64);
    QST(qb1, qb3, 64);
    QST(qa1, qa3, 128);
    barrier_nodrain();

    for (int t = 0; t < NT; t += 2) {
        // even step t: consume LDS[0]; WLDS(qb)=W(t+1); refill qb with W(t+3)
        MFMA_PH(0);
        {
            WLDS(qb1, qb3, 1);
            if (t + 2 < NT) ASZ((t + 2) * 64);
            if (t + 3 < NT) QST(qb1, qb3, (t + 3) * 64);
            barrier_nodrain();
        }
        // odd step t+1: consume LDS[1]; WLDS(qa)=W(t+2); refill qa with W(t+4)
        MFMA_PH(1);
        if (t + 2 < NT) {
            WLDS(qa1, qa3, 0);
            if (t + 3 < NT) ASZ((t + 3) * 64);
            if (t + 4 < NT) QST(qa1, qa3, (t + 4) * 64);
            barrier_nodrain();
        }
    }
#undef ASZ
#undef QST
#undef WLDS
#undef MFMA_PH

    // Epilogue: silu(gate)*up -> inter (row-major).
    const int orow = (lane >> 4) * 4;
#pragma unroll
    for (int mi = 0; mi < 4; mi++)
#pragma unroll
        for (int ni = 0; ni < 2; ni++) {
#pragma unroll
            for (int r = 0; r < 4; r++) {
                int m = m0 + wm * 64 + mi * 16 + orow + r;
                int c = n0 + wn * 32 + ni * 16 + lr;
                float g = acc1[mi][ni][r];
                float u = acc3[mi][ni][r];
                float s = g / (1.0f + __expf(-g));
                inter[(size_t)m * F_DIM + c] = (bf16)(s * u);
            }
        }
}

// ---------------------------------------------------------------------------
// Down proj, split-K: tile 128x64, wave 64x32, same 2-deep-q pipeline.
template<int SPLITK>
__global__ __launch_bounds__(256, 3)
void gemm_down(const bf16* __restrict__ A, const int* __restrict__ Wq,
               const float* __restrict__ Sc, const float* __restrict__ Zr,
               float* __restrict__ partials) {
    constexpr int KD = F_DIM;
    constexpr int KC = KD / SPLITK;
    constexpr int NT = KC / 64;                     // 56 (even)
    __shared__ __align__(16) bf16 As[2][128 * 64];  // 32 KB
    __shared__ __align__(16) bf16 Bs[2][64 * 64];   // 16 KB

    const int l    = xcd_remap(blockIdx.x, 32 * SPLITK);
    const int bx   = l & 3;
    const int by   = (l >> 2) & 63;
    const int bz   = l >> 8;
    const int tid  = threadIdx.x;
    const int lane = tid & 63;
    const int wid  = tid >> 6;
    const int wm   = wid >> 1, wn = wid & 1;
    const int lr   = lane & 15;
    const int lk   = (lane >> 4) * 8;
    const int m0   = bx * 128;
    const int n0   = by * 64;
    const int grp  = by;
    const int kbeg = bz * KC;

    const int a_r = tid >> 2;
    const int a_c = (tid & 3) * 8;
    const int b_r = (tid >> 4) * 4;
    const int b_c = (tid & 15) * 4;

    f32x4 acc[4][2];
    const f32x4 zf = {0.f, 0.f, 0.f, 0.f};
#pragma unroll
    for (int i = 0; i < 4; i++)
#pragma unroll
        for (int j = 0; j < 2; j++) acc[i][j] = zf;

    bf16x8 areg[4];
    int4   qa[4], qb[4];
    float4 sr, zr;

#define ASZ(K0)                                                                   \
    {                                                                             \
        _Pragma("unroll")                                                         \
        for (int p = 0; p < 2; p++)                                               \
            _Pragma("unroll")                                                     \
            for (int h = 0; h < 2; h++)                                           \
                areg[p * 2 + h] = *(const bf16x8*)(A + (size_t)(m0 + a_r + 64 * p) * KD + kbeg + (K0) + a_c + 32 * h); \
        sr = *(const float4*)(Sc + (size_t)grp * KD + kbeg + (K0) + b_c);         \
        zr = *(const float4*)(Zr + (size_t)grp * KD + kbeg + (K0) + b_c);         \
    }

#define QST(Q, K0)                                                                \
    {                                                                             \
        _Pragma("unroll")                                                         \
        for (int i = 0; i < 4; i++)                                               \
            Q[i] = *(const int4*)(Wq + (size_t)(n0 + b_r + i) * KD + kbeg + (K0) + b_c); \
    }

#define WLDS(Q, nb)                                                               \
    {                                                                             \
        _Pragma("unroll")                                                         \
        for (int p = 0; p < 2; p++)                                               \
            _Pragma("unroll")                                                     \
            for (int h = 0; h < 2; h++)                                           \
                *(bf16x8*)&As[nb][swz(a_r + 64 * p, a_c + 32 * h)] = areg[p * 2 + h]; \
        float4 nz;                                                                \
        nz.x = -zr.x * sr.x; nz.y = -zr.y * sr.y;                                 \
        nz.z = -zr.z * sr.z; nz.w = -zr.w * sr.w;                                 \
        _Pragma("unroll")                                                         \
        for (int i = 0; i < 4; i++) {                                             \
            bf16x4 v;                                                             \
            v[0] = (bf16)fmaf((float)Q[i].x, sr.x, nz.x);                         \
            v[1] = (bf16)fmaf((float)Q[i].y, sr.y, nz.y);                         \
            v[2] = (bf16)fmaf((float)Q[i].z, sr.z, nz.z);                         \
            v[3] = (bf16)fmaf((float)Q[i].w, sr.w, nz.w);                         \
            *(bf16x4*)&Bs[nb][swz(b_r + i, b_c)] = v;                             \
        }                                                                         \
    }

#define MFMA_PH(nb)                                                               \
    {                                                                             \
        _Pragma("unroll")                                                         \
        for (int kk = 0; kk < 2; kk++) {                                          \
            bf16x8 af[4], bfr[2];                                                 \
            _Pragma("unroll")                                                     \
            for (int mi = 0; mi < 4; mi++)                                        \
                af[mi] = *(const bf16x8*)&As[nb][swz(wm * 64 + mi * 16 + lr, kk * 32 + lk)]; \
            _Pragma("unroll")                                                     \
            for (int ni = 0; ni < 2; ni++)                                        \
                bfr[ni] = *(const bf16x8*)&Bs[nb][swz(wn * 32 + ni * 16 + lr, kk * 32 + lk)]; \
            _Pragma("unroll")                                                     \
            for (int mi = 0; mi < 4; mi++)                                        \
                _Pragma("unroll")                                                 \
                for (int ni = 0; ni < 2; ni++)                                    \
                    acc[mi][ni] = __builtin_amdgcn_mfma_f32_16x16x32_bf16(af[mi], bfr[ni], acc[mi][ni], 0, 0, 0); \
        }                                                                         \
    }

    ASZ(0);
    QST(qa, 0);
    WLDS(qa, 0);
    ASZ(64);
    QST(qb, 64);
    QST(qa, 128);
    barrier_nodrain();

    for (int t = 0; t < NT; t += 2) {
        MFMA_PH(0);
        {
            WLDS(qb, 1);
            if (t + 2 < NT) ASZ((t + 2) * 64);
            if (t + 3 < NT) QST(qb, (t + 3) * 64);
            barrier_nodrain();
        }
        MFMA_PH(1);
        if (t + 2 < NT) {
            WLDS(qa, 0);
            if (t + 3 < NT) ASZ((t + 3) * 64);
            if (t + 4 < NT) QST(qa, (t + 4) * 64);
            barrier_nodrain();
        }
    }
#undef ASZ
#undef QST
#undef WLDS
#undef MFMA_PH

    float* po = partials + (size_t)bz * T_DIM * H_DIM;
    const int orow = (lane >> 4) * 4;
#pragma unroll
    for (int mi = 0; mi < 4; mi++)
#pragma unroll
        for (int ni = 0; ni < 2; ni++) {
#pragma unroll
            for (int r = 0; r < 4; r++) {
                int m = m0 + wm * 64 + mi * 16 + orow + r;
                int c = n0 + wn * 32 + ni * 16 + lr;
                po[(size_t)m * H_DIM + c] = acc[mi][ni][r];
            }
        }
}

// ---------------------------------------------------------------------------
template<int S>
__global__ void reduce_kernel(const float* __restrict__ partials, float* __restrict__ out) {
    size_t i = ((size_t)blockIdx.x * 256 + threadIdx.x) * 4;
    f32x4 a = *(const f32x4*)(partials + i);
#pragma unroll
    for (int s = 1; s < S; s++)
        a += *(const f32x4*)(partials + (size_t)s * T_DIM * H_DIM + i);
    *(f32x4*)(out + i) = a;
}

// ---------------------------------------------------------------------------
extern "C" void kernel_launch(void* const* d_in, const int* in_sizes, int n_in,
                              void* d_out, int out_size, void* d_ws, size_t ws_size,
                              hipStream_t stream) {
    const float* x   = (const float*)d_in[0];
    const int*   w1q = (const int*)d_in[1];
    const float* w1s = (const float*)d_in[2];
    const float* w1z = (const float*)d_in[3];
    const int*   w2q = (const int*)d_in[4];
    const float* w2s = (const float*)d_in[5];
    const float* w2z = (const float*)d_in[6];
    const int*   w3q = (const int*)d_in[7];
    const float* w3s = (const float*)d_in[8];
    const float* w3z = (const float*)d_in[9];

    bf16*  xb    = (bf16*)d_ws;                         // [512][4096]  bf16
    bf16*  inter = xb + (size_t)T_DIM * H_DIM;          // [512][14336] bf16
    float* parts = (float*)(inter + (size_t)T_DIM * F_DIM);

    const size_t base   = (size_t)T_DIM * H_DIM * 2 + (size_t)T_DIM * F_DIM * 2;
    const size_t pbytes = (size_t)T_DIM * H_DIM * 4;

    cvt_x_kernel<<<dim3(2048), dim3(256), 0, stream>>>(x, xb);

    gemm_gateup<<<dim3(896), dim3(256), 0, stream>>>(
        xb, w1q, w1s, w1z, w3q, w3s, w3z, inter);

    if (ws_size >= base + 4 * pbytes) {
        gemm_down<4><<<dim3(1024), dim3(256), 0, stream>>>(inter, w2q, w2s, w2z, parts);
        reduce_kernel<4><<<dim3(2048), dim3(256), 0, stream>>>(parts, (float*)d_out);
    } else if (ws_size >= base + 2 * pbytes) {
        gemm_down<2><<<dim3(512), dim3(256), 0, stream>>>(inter, w2q, w2s, w2z, parts);
        reduce_kernel<2><<<dim3(2048), dim3(256), 0, stream>>>(parts, (float*)d_out);
    } else {
        gemm_down<1><<<dim3(256), dim3(256), 0, stream>>>(inter, w2q, w2s, w2z, parts);
        reduce_kernel<1><<<dim3(2048), dim3(256), 0, stream>>>(parts, (float*)d_out);
    }
}